// Round 1
// baseline (12960.431 us; speedup 1.0000x reference)
//
#include <hip/hip_runtime.h>
#include <hip/hip_bf16.h>

// ---------------- constants ----------------
#define Bn 4
#define Tn 1024
#define Cn 768
#define Hn 12
#define Nn 64
#define Ln 12
#define Vn 50304
#define Qn 256
#define NCn 4              // T/Q chunks
#define BTn (Bn*Tn)        // 4096
#define C3n (3*Cn)         // 2304
#define GN_EPS 6.4e-4f     // 1e-5 * 64
#define LN_EPS 1e-5f

// ---------------- helpers ----------------
__device__ __forceinline__ float blocksum256(float v, float* red) {
#pragma unroll
    for (int o = 32; o > 0; o >>= 1) v += __shfl_down(v, o, 64);
    if ((threadIdx.x & 63) == 0) red[threadIdx.x >> 6] = v;
    __syncthreads();
    v = red[0] + red[1] + red[2] + red[3];
    __syncthreads();
    return v;
}

// ---------------- embedding ----------------
__global__ __launch_bounds__(256) void k_embed(const int* __restrict__ idx,
        const float* __restrict__ wte, const float* __restrict__ wpe,
        float* __restrict__ x) {
    int row = blockIdx.x;            // b*T + t
    int pos = row & (Tn - 1);        // t
    int tok = idx[row];
    const float* wr = wte + (size_t)tok * Cn;
    const float* pr = wpe + (size_t)pos * Cn;
    float* xr = x + (size_t)row * Cn;
    for (int c = threadIdx.x; c < Cn; c += 256) xr[c] = wr[c] + pr[c];
}

// ---------------- layernorm ----------------
// row = blockIdx.x*rstride + roff  (input row); output row = blockIdx.x (compact)
__global__ __launch_bounds__(256) void k_ln(const float* __restrict__ x,
        const float* __restrict__ w, const float* __restrict__ b,
        float* __restrict__ out, int rstride, int roff) {
    __shared__ float red[4];
    int row = blockIdx.x * rstride + roff;
    const float* xr = x + (size_t)row * Cn;
    int tid = threadIdx.x;
    float v0 = xr[tid], v1 = xr[tid + 256], v2 = xr[tid + 512];
    float mu = blocksum256(v0 + v1 + v2, red) * (1.f / Cn);
    float d0 = v0 - mu, d1 = v1 - mu, d2 = v2 - mu;
    float var = blocksum256(d0 * d0 + d1 * d1 + d2 * d2, red) * (1.f / Cn);
    float rs = rsqrtf(var + LN_EPS);
    float* orow = out + (size_t)blockIdx.x * Cn;
    orow[tid]       = d0 * rs * w[tid]       + b[tid];
    orow[tid + 256] = d1 * rs * w[tid + 256] + b[tid + 256];
    orow[tid + 512] = d2 * rs * w[tid + 512] + b[tid + 512];
}

// ---------------- token-shift mixes ----------------
__global__ __launch_bounds__(256) void k_mix4(const float* __restrict__ xn,
        const float* __restrict__ mk, const float* __restrict__ mv,
        const float* __restrict__ mr, const float* __restrict__ mg,
        float* __restrict__ xk, float* __restrict__ xv,
        float* __restrict__ xr, float* __restrict__ xg) {
    int i = blockIdx.x * 256 + threadIdx.x;          // < BT*C
    int c = i % Cn;
    int t = (i / Cn) & (Tn - 1);
    float cur = xn[i];
    float prev = (t == 0) ? 0.f : xn[i - Cn];
    float xx = prev - cur;
    xk[i] = cur + xx * mk[c];
    xv[i] = cur + xx * mv[c];
    xr[i] = cur + xx * mr[c];
    xg[i] = cur + xx * mg[c];
}

__global__ __launch_bounds__(256) void k_mix2(const float* __restrict__ xn,
        const float* __restrict__ mk, const float* __restrict__ mr,
        float* __restrict__ xk, float* __restrict__ xr) {
    int i = blockIdx.x * 256 + threadIdx.x;
    int c = i % Cn;
    int t = (i / Cn) & (Tn - 1);
    float cur = xn[i];
    float prev = (t == 0) ? 0.f : xn[i - Cn];
    float xx = prev - cur;
    xk[i] = cur + xx * mk[c];
    xr[i] = cur + xx * mr[c];
}

// ---------------- generic tiled f32 GEMM ----------------
// Cout[M,N] = act(A[M,K] @ W[K,N] + bias[N]) (+ Cout if RES)
// ACT: 0 none, 1 silu, 2 relu^2, 3 sigmoid
template<int ACT, int RES>
__global__ __launch_bounds__(256) void k_gemm(const float* __restrict__ A,
        const float* __restrict__ W, const float* __restrict__ bias,
        float* __restrict__ Cout, int M, int N, int K) {
    __shared__ float As[16][64];
    __shared__ float Bs[16][64];
    const int tid = threadIdx.x;
    const int tx = tid & 15, ty = tid >> 4;
    const int m0 = blockIdx.y * 64, n0 = blockIdx.x * 64;
    float acc[4][4] = {};
    const int lm = tid >> 2;          // 0..63 (A row)
    const int lk = (tid & 3) << 2;    // 0,4,8,12 (A k)
    const int wk = tid >> 4;          // 0..15 (W row)
    const int wn = (tid & 15) << 2;   // W col
    for (int kb = 0; kb < K; kb += 16) {
        float4 av = *(const float4*)(A + (size_t)(m0 + lm) * K + kb + lk);
        As[lk + 0][lm] = av.x; As[lk + 1][lm] = av.y;
        As[lk + 2][lm] = av.z; As[lk + 3][lm] = av.w;
        *(float4*)&Bs[wk][wn] = *(const float4*)(W + (size_t)(kb + wk) * N + n0 + wn);
        __syncthreads();
#pragma unroll
        for (int kk = 0; kk < 16; ++kk) {
            float4 a = *(const float4*)&As[kk][ty << 2];
            float4 bb = *(const float4*)&Bs[kk][tx << 2];
            float avr[4] = {a.x, a.y, a.z, a.w};
            float bvr[4] = {bb.x, bb.y, bb.z, bb.w};
#pragma unroll
            for (int i = 0; i < 4; ++i)
#pragma unroll
                for (int j = 0; j < 4; ++j)
                    acc[i][j] = fmaf(avr[i], bvr[j], acc[i][j]);
        }
        __syncthreads();
    }
#pragma unroll
    for (int i = 0; i < 4; ++i) {
        int m = m0 + (ty << 2) + i;
#pragma unroll
        for (int j = 0; j < 4; ++j) {
            int n = n0 + (tx << 2) + j;
            float v = acc[i][j] + bias[n];
            if (ACT == 1) v = v / (1.f + __expf(-v));
            if (ACT == 2) { float r = fmaxf(v, 0.f); v = r * r; }
            if (ACT == 3) v = 1.f / (1.f + __expf(-v));
            size_t o = (size_t)m * N + n;
            if (RES) v += Cout[o];
            Cout[o] = v;
        }
    }
}

// ---------------- attention: per-chunk state contribution ----------------
// A_c[m,n] = sum_j k[j][m] * w^(Q-1-j) * v[j][n];  blockIdx = (b*H+h)*NC + c
__global__ __launch_bounds__(256) void k_chunkA(const float* __restrict__ kbuf,
        const float* __restrict__ vbuf, const float* __restrict__ td,
        float* __restrict__ Abuf) {
    int c = blockIdx.x & 3;
    int bh = blockIdx.x >> 2;
    int h = bh % Hn, b = bh / Hn;
    float lw = -__expf(td[h]);                    // log(w)
    __shared__ float kd[8][64], vl[8][64];
    int tn = threadIdx.x & 63;
    int tm0 = (threadIdx.x >> 6) * 16;
    float acc[16] = {};
    const size_t base = ((size_t)(b * Tn + c * Qn)) * Cn + h * Nn;
    int jr = threadIdx.x >> 6;                    // 0..3
    for (int j0 = 0; j0 < Qn; j0 += 8) {
#pragma unroll
        for (int rr = 0; rr < 2; ++rr) {
            int jj = jr + rr * 4;
            int j = j0 + jj;
            float dec = __expf(lw * (float)(Qn - 1 - j));
            kd[jj][tn] = kbuf[base + (size_t)j * Cn + tn] * dec;
            vl[jj][tn] = vbuf[base + (size_t)j * Cn + tn];
        }
        __syncthreads();
#pragma unroll
        for (int j = 0; j < 8; ++j) {
            float vv = vl[j][tn];
#pragma unroll
            for (int m = 0; m < 16; ++m)
                acc[m] = fmaf(kd[j][tm0 + m], vv, acc[m]);
        }
        __syncthreads();
    }
    size_t ao = ((size_t)blockIdx.x * Nn + tm0) * Nn + tn;
#pragma unroll
    for (int m = 0; m < 16; ++m) Abuf[ao + (size_t)m * Nn] = acc[m];
}

// ---------------- attention: prefix over chunks ----------------
// S[c] = ws*S[c-1] + A[c-1], S[0]=0;  blockIdx = b*H+h
__global__ __launch_bounds__(256) void k_prefix(const float* __restrict__ Abuf,
        const float* __restrict__ td, float* __restrict__ Sbuf) {
    int h = blockIdx.x % Hn;
    float lw = -__expf(td[h]);
    float ws = __expf(lw * (float)Qn);
    size_t base = (size_t)blockIdx.x * NCn * Nn * Nn;
    for (int e = threadIdx.x; e < Nn * Nn; e += 256) {
        float s = 0.f;
#pragma unroll
        for (int c = 0; c < NCn; ++c) {
            Sbuf[base + (size_t)c * Nn * Nn + e] = s;
            s = ws * s + Abuf[base + (size_t)c * Nn * Nn + e];
        }
    }
}

// ---------------- attention: y for a 64-row block of a chunk ----------------
// blockIdx = (((b*H+h)*NC + c)*4 + ib)
__global__ __launch_bounds__(256) void k_attny(const float* __restrict__ rbuf,
        const float* __restrict__ kbuf, const float* __restrict__ vbuf,
        const float* __restrict__ Sbuf, const float* __restrict__ td,
        const float* __restrict__ tf, float* __restrict__ ybuf) {
    int x = blockIdx.x;
    int ib = x & 3; x >>= 2;
    int c = x & 3;
    int bh = x >> 2;
    int h = bh % Hn, b = bh / Hn;
    float lw = -__expf(td[h]);
    float u = tf[h];
    __shared__ float rl[64][65];
    __shared__ float tl[64][65];
    __shared__ float att[64][257];
    const int i0 = ib * 64;
    const size_t rowbase = ((size_t)(b * Tn + c * Qn)) * Cn + h * Nn;
    const int tn = threadIdx.x & 63;
    const int tg = threadIdx.x >> 6;
    const int ii0 = (threadIdx.x >> 4) * 4;   // 0..60 step 4 (row group)
    const int cc0 = (threadIdx.x & 15) * 4;   // 0..60 step 4 (col group)

    // load r rows for this i-block
#pragma unroll
    for (int rr = 0; rr < 16; ++rr) {
        int i = tg * 16 + rr;
        rl[i][tn] = rbuf[rowbase + (size_t)(i0 + i) * Cn + tn];
    }
    __syncthreads();

    // phase A: att[ii][j] = (r_i . k_j) * Wmat
    for (int jt = 0; jt <= ib; ++jt) {
#pragma unroll
        for (int rr = 0; rr < 16; ++rr) {
            int j = tg * 16 + rr;
            tl[j][tn] = kbuf[rowbase + (size_t)(jt * 64 + j) * Cn + tn];
        }
        __syncthreads();
        float a4[4][4] = {};
#pragma unroll 4
        for (int m = 0; m < 64; ++m) {
            float rv[4], kv[4];
#pragma unroll
            for (int q = 0; q < 4; ++q) { rv[q] = rl[ii0 + q][m]; kv[q] = tl[cc0 + q][m]; }
#pragma unroll
            for (int aa = 0; aa < 4; ++aa)
#pragma unroll
                for (int bb = 0; bb < 4; ++bb)
                    a4[aa][bb] = fmaf(rv[aa], kv[bb], a4[aa][bb]);
        }
#pragma unroll
        for (int aa = 0; aa < 4; ++aa)
#pragma unroll
            for (int bb = 0; bb < 4; ++bb) {
                int i = i0 + ii0 + aa;
                int j = jt * 64 + cc0 + bb;
                int d = i - j;
                float f = (d > 0) ? __expf(lw * (float)(d - 1)) : ((d == 0) ? u : 0.f);
                att[ii0 + aa][j] = a4[aa][bb] * f;
            }
        __syncthreads();
    }

    // S term: y = (r @ S) * w^i
    {
        size_t sbase = ((size_t)bh * NCn + c) * (Nn * Nn);
#pragma unroll
        for (int rr = 0; rr < 16; ++rr) {
            int m = tg * 16 + rr;
            tl[m][tn] = Sbuf[sbase + (size_t)m * Nn + tn];
        }
        __syncthreads();
    }
    float yacc[4][4] = {};
#pragma unroll 4
    for (int m = 0; m < 64; ++m) {
        float rv[4], sv[4];
#pragma unroll
        for (int q = 0; q < 4; ++q) { rv[q] = rl[ii0 + q][m]; sv[q] = tl[m][cc0 + q]; }
#pragma unroll
        for (int aa = 0; aa < 4; ++aa)
#pragma unroll
            for (int bb = 0; bb < 4; ++bb)
                yacc[aa][bb] = fmaf(rv[aa], sv[bb], yacc[aa][bb]);
    }
#pragma unroll
    for (int aa = 0; aa < 4; ++aa) {
        float f = __expf(lw * (float)(i0 + ii0 + aa));
#pragma unroll
        for (int bb = 0; bb < 4; ++bb) yacc[aa][bb] *= f;
    }
    __syncthreads();

    // phase B: y += att @ v
    for (int jt = 0; jt <= ib; ++jt) {
#pragma unroll
        for (int rr = 0; rr < 16; ++rr) {
            int j = tg * 16 + rr;
            tl[j][tn] = vbuf[rowbase + (size_t)(jt * 64 + j) * Cn + tn];
        }
        __syncthreads();
#pragma unroll 4
        for (int j = 0; j < 64; ++j) {
            float av[4], vv[4];
#pragma unroll
            for (int q = 0; q < 4; ++q) { av[q] = att[ii0 + q][jt * 64 + j]; vv[q] = tl[j][cc0 + q]; }
#pragma unroll
            for (int aa = 0; aa < 4; ++aa)
#pragma unroll
                for (int bb = 0; bb < 4; ++bb)
                    yacc[aa][bb] = fmaf(av[aa], vv[bb], yacc[aa][bb]);
        }
        __syncthreads();
    }

#pragma unroll
    for (int aa = 0; aa < 4; ++aa)
#pragma unroll
        for (int bb = 0; bb < 4; ++bb)
            ybuf[rowbase + (size_t)(i0 + ii0 + aa) * Cn + cc0 + bb] = yacc[aa][bb];
}

// ---------------- groupnorm (per token,head) + gate, in place ----------------
__global__ __launch_bounds__(768) void k_gngate(float* __restrict__ y,
        const float* __restrict__ g, const float* __restrict__ gw,
        const float* __restrict__ gb) {
    int t = blockIdx.x;
    int h = threadIdx.x >> 6, n = threadIdx.x & 63;
    size_t o = (size_t)t * Cn + h * 64 + n;
    float v = y[o];
    float s = v;
#pragma unroll
    for (int q = 32; q > 0; q >>= 1) s += __shfl_xor(s, q, 64);
    float mu = s * (1.f / 64.f);
    float d = v - mu;
    float qq = d * d;
#pragma unroll
    for (int q = 32; q > 0; q >>= 1) qq += __shfl_xor(qq, q, 64);
    float var = qq * (1.f / 64.f);
    float outv = d * rsqrtf(var + GN_EPS) * gw[h * 64 + n] + gb[h * 64 + n];
    y[o] = outv * g[o];
}

// ---------------- cmix combine: x += sig * hv ----------------
__global__ __launch_bounds__(256) void k_combine(float* __restrict__ x,
        const float* __restrict__ sg, const float* __restrict__ hv) {
    int i = blockIdx.x * 256 + threadIdx.x;
    x[i] = fmaf(sg[i], hv[i], x[i]);
}

// ---------------- head: out[b,v] = xf[b,:] . wte[v,:] ----------------
__global__ __launch_bounds__(256) void k_head(const float* __restrict__ xf,
        const float* __restrict__ wte, float* __restrict__ out) {
    __shared__ float red[4][4];
    int v = blockIdx.x;
    int tid = threadIdx.x;
    const float* wr = wte + (size_t)v * Cn;
    float a0 = 0, a1 = 0, a2 = 0, a3 = 0;
    for (int c = tid; c < Cn; c += 256) {
        float wv = wr[c];
        a0 = fmaf(wv, xf[c], a0);
        a1 = fmaf(wv, xf[Cn + c], a1);
        a2 = fmaf(wv, xf[2 * Cn + c], a2);
        a3 = fmaf(wv, xf[3 * Cn + c], a3);
    }
#pragma unroll
    for (int o = 32; o > 0; o >>= 1) {
        a0 += __shfl_down(a0, o, 64); a1 += __shfl_down(a1, o, 64);
        a2 += __shfl_down(a2, o, 64); a3 += __shfl_down(a3, o, 64);
    }
    if ((tid & 63) == 0) {
        int w8 = tid >> 6;
        red[w8][0] = a0; red[w8][1] = a1; red[w8][2] = a2; red[w8][3] = a3;
    }
    __syncthreads();
    if (tid < 4)
        out[(size_t)tid * Vn + v] = red[0][tid] + red[1][tid] + red[2][tid] + red[3][tid];
}

// ---------------- launch ----------------
extern "C" void kernel_launch(void* const* d_in, const int* in_sizes, int n_in,
                              void* d_out, int out_size, void* d_ws, size_t ws_size,
                              hipStream_t stream) {
    const int*   idx    = (const int*)  d_in[0];
    const float* wte    = (const float*)d_in[1];
    const float* wpe    = (const float*)d_in[2];
    const float* ln1_w  = (const float*)d_in[3];
    const float* ln1_b  = (const float*)d_in[4];
    const float* ln2_w  = (const float*)d_in[5];
    const float* ln2_b  = (const float*)d_in[6];
    const float* maa_tk = (const float*)d_in[7];
    const float* maa_tv = (const float*)d_in[8];
    const float* maa_tr = (const float*)d_in[9];
    const float* maa_tg = (const float*)d_in[10];
    const float* tdecay = (const float*)d_in[11];
    const float* tfaaaa = (const float*)d_in[12];
    const float* Wr     = (const float*)d_in[13];
    const float* br     = (const float*)d_in[14];
    const float* Wk     = (const float*)d_in[15];
    const float* bk     = (const float*)d_in[16];
    const float* Wv     = (const float*)d_in[17];
    const float* bv     = (const float*)d_in[18];
    const float* Wg     = (const float*)d_in[19];
    const float* bg     = (const float*)d_in[20];
    const float* Wo     = (const float*)d_in[21];
    const float* bo     = (const float*)d_in[22];
    const float* gn_w   = (const float*)d_in[23];
    const float* gn_b   = (const float*)d_in[24];
    const float* cmaa_k = (const float*)d_in[25];
    const float* cmaa_r = (const float*)d_in[26];
    const float* Wck    = (const float*)d_in[27];
    const float* bck    = (const float*)d_in[28];
    const float* Wcv    = (const float*)d_in[29];
    const float* bcv    = (const float*)d_in[30];
    const float* Wcr    = (const float*)d_in[31];
    const float* bcr    = (const float*)d_in[32];
    const float* lnf_w  = (const float*)d_in[33];
    const float* lnf_b  = (const float*)d_in[34];
    float* out = (float*)d_out;

    float* ws = (float*)d_ws;
    size_t p = 0;
    auto alloc = [&](size_t n) { float* q = ws + p; p += n; return q; };
    const size_t SZ = (size_t)BTn * Cn;        // 3.15M floats
    float* X  = alloc(SZ);
    float* XN = alloc(SZ);                     // also reused as Y
    float* M1 = alloc(SZ);
    float* M2 = alloc(SZ);
    float* M3 = alloc(SZ);
    float* M4 = alloc(SZ);
    float* R1 = alloc(SZ);                     // r; later hv
    float* R2 = alloc(SZ);                     // k; later sig(rr)
    float* R3 = alloc(SZ);                     // v
    float* R4 = alloc(SZ);                     // g
    float* H3 = alloc((size_t)BTn * C3n);      // 9.4M floats
    float* Ab = alloc((size_t)Bn * Hn * NCn * Nn * Nn);
    float* Sb = alloc((size_t)Bn * Hn * NCn * Nn * Nn);
    float* XF = alloc((size_t)Bn * Cn);
    if (p * sizeof(float) > ws_size) return;   // workspace too small — bail

    float* Y = XN;  // alias: XN dead once mixes are computed; Y dead before ln2 writes XN

    const int EW = (BTn * Cn) / 256;           // elementwise grid
    dim3 gSq(Cn / 64, BTn / 64);               // (12,64) for N=768
    dim3 gCk(C3n / 64, BTn / 64);              // (36,64) for N=2304

    k_embed<<<BTn, 256, 0, stream>>>(idx, wte, wpe, X);

    for (int l = 0; l < Ln; ++l) {
        const size_t wo = (size_t)l * Cn * Cn;
        const float* td = tdecay + l * Hn;
        const float* tf = tfaaaa + l * Hn;

        // ---- tmix ----
        k_ln<<<BTn, 256, 0, stream>>>(X, ln1_w + l * Cn, ln1_b + l * Cn, XN, 1, 0);
        k_mix4<<<EW, 256, 0, stream>>>(XN, maa_tk + l * Cn, maa_tv + l * Cn,
                                       maa_tr + l * Cn, maa_tg + l * Cn, M1, M2, M3, M4);
        k_gemm<0, 0><<<gSq, 256, 0, stream>>>(M3, Wr + wo, br + l * Cn, R1, BTn, Cn, Cn); // r
        k_gemm<0, 0><<<gSq, 256, 0, stream>>>(M1, Wk + wo, bk + l * Cn, R2, BTn, Cn, Cn); // k
        k_gemm<0, 0><<<gSq, 256, 0, stream>>>(M2, Wv + wo, bv + l * Cn, R3, BTn, Cn, Cn); // v
        k_gemm<1, 0><<<gSq, 256, 0, stream>>>(M4, Wg + wo, bg + l * Cn, R4, BTn, Cn, Cn); // g=silu
        k_chunkA<<<Bn * Hn * NCn, 256, 0, stream>>>(R2, R3, td, Ab);
        k_prefix<<<Bn * Hn, 256, 0, stream>>>(Ab, td, Sb);
        k_attny<<<Bn * Hn * NCn * 4, 256, 0, stream>>>(R1, R2, R3, Sb, td, tf, Y);
        k_gngate<<<BTn, 768, 0, stream>>>(Y, R4, gn_w + l * Cn, gn_b + l * Cn);
        k_gemm<0, 1><<<gSq, 256, 0, stream>>>(Y, Wo + wo, bo + l * Cn, X, BTn, Cn, Cn);   // X += y@Wo+bo

        // ---- cmix ----
        k_ln<<<BTn, 256, 0, stream>>>(X, ln2_w + l * Cn, ln2_b + l * Cn, XN, 1, 0);
        k_mix2<<<EW, 256, 0, stream>>>(XN, cmaa_k + l * Cn, cmaa_r + l * Cn, M1, M3);
        k_gemm<2, 0><<<gCk, 256, 0, stream>>>(M1, Wck + (size_t)l * Cn * C3n,
                                              bck + l * C3n, H3, BTn, C3n, Cn);           // relu^2
        k_gemm<0, 0><<<gSq, 256, 0, stream>>>(H3, Wcv + (size_t)l * C3n * Cn,
                                              bcv + l * Cn, R1, BTn, Cn, C3n);            // hv
        k_gemm<3, 0><<<gSq, 256, 0, stream>>>(M3, Wcr + wo, bcr + l * Cn, R2, BTn, Cn, Cn); // sig
        k_combine<<<EW, 256, 0, stream>>>(X, R2, R1);
    }

    k_ln<<<Bn, 256, 0, stream>>>(X, lnf_w, lnf_b, XF, Tn, Tn - 1);
    k_head<<<Vn, 256, 0, stream>>>(XF, wte, out);
}

// Round 2
// 4836.169 us; speedup vs baseline: 2.6799x; 2.6799x over previous
//
#include <hip/hip_runtime.h>
#include <hip/hip_bf16.h>

// ---------------- constants ----------------
#define Bn 4
#define Tn 1024
#define Cn 768
#define Hn 12
#define Nn 64
#define Ln 12
#define Vn 50304
#define Qn 256
#define NCn 4              // T/Q chunks
#define BTn (Bn*Tn)        // 4096
#define C3n (3*Cn)         // 2304
#define RS 3072            // fused rkvg row stride
#define GN_EPS 6.4e-4f     // 1e-5 * 64
#define LN_EPS 1e-5f

typedef __hip_bfloat16 bf16;
typedef __attribute__((ext_vector_type(8))) __bf16 bf16x8;
typedef __attribute__((ext_vector_type(4))) float f32x4;

// ---------------- helpers ----------------
__device__ __forceinline__ float blocksum256(float v, float* red) {
#pragma unroll
    for (int o = 32; o > 0; o >>= 1) v += __shfl_down(v, o, 64);
    if ((threadIdx.x & 63) == 0) red[threadIdx.x >> 6] = v;
    __syncthreads();
    v = red[0] + red[1] + red[2] + red[3];
    __syncthreads();
    return v;
}

// ---------------- embedding ----------------
__global__ __launch_bounds__(256) void k_embed(const int* __restrict__ idx,
        const float* __restrict__ wte, const float* __restrict__ wpe,
        float* __restrict__ x) {
    int row = blockIdx.x;
    int pos = row & (Tn - 1);
    int tok = idx[row];
    const float* wr = wte + (size_t)tok * Cn;
    const float* pr = wpe + (size_t)pos * Cn;
    float* xr = x + (size_t)row * Cn;
    for (int c = threadIdx.x; c < Cn; c += 256) xr[c] = wr[c] + pr[c];
}

// ---------------- weight transpose + bf16 cast ----------------
// src fp32 [K,N] (per-layer stride sstr), dst bf16 [N,K] (per-layer stride dstr)
__global__ __launch_bounds__(256) void k_wt(const float* __restrict__ src,
        bf16* __restrict__ dst, int N, int K, size_t sstr, size_t dstr) {
    __shared__ float t[64][65];
    src += (size_t)blockIdx.z * sstr;
    dst += (size_t)blockIdx.z * dstr;
    int n0 = blockIdx.x * 64, k0 = blockIdx.y * 64;
    int c = threadIdx.x & 63, r4 = threadIdx.x >> 6;
#pragma unroll
    for (int rr = 0; rr < 16; ++rr) {
        int k = r4 * 16 + rr;
        t[k][c] = src[(size_t)(k0 + k) * N + n0 + c];
    }
    __syncthreads();
#pragma unroll
    for (int rr = 0; rr < 16; ++rr) {
        int n = r4 * 16 + rr;
        dst[(size_t)(n0 + n) * K + k0 + c] = __float2bfloat16(t[c][n]);
    }
}

// ---------------- bias packing ----------------
__global__ __launch_bounds__(256) void k_packb4(const float* __restrict__ b0,
        const float* __restrict__ b1, const float* __restrict__ b2,
        const float* __restrict__ b3, float* __restrict__ dst) {
    int i = blockIdx.x * 256 + threadIdx.x;          // < L*3072
    int l = i / RS, c = i % RS;
    float v = (c < 768) ? b0[l * 768 + c]
            : (c < 1536) ? b1[l * 768 + c - 768]
            : (c < 2304) ? b2[l * 768 + c - 1536]
            : b3[l * 768 + c - 2304];
    dst[i] = v;
}
__global__ __launch_bounds__(256) void k_packb2(const float* __restrict__ bck,
        const float* __restrict__ bcr, float* __restrict__ dst) {
    int i = blockIdx.x * 256 + threadIdx.x;
    int l = i / RS, c = i % RS;
    dst[i] = (c < 2304) ? bck[l * 2304 + c] : bcr[l * 768 + c - 2304];
}

// ---------------- layernorm (fp32 -> fp32) ----------------
__global__ __launch_bounds__(256) void k_ln(const float* __restrict__ x,
        const float* __restrict__ w, const float* __restrict__ b,
        float* __restrict__ out, int rstride, int roff) {
    __shared__ float red[4];
    int row = blockIdx.x * rstride + roff;
    const float* xr = x + (size_t)row * Cn;
    int tid = threadIdx.x;
    float v0 = xr[tid], v1 = xr[tid + 256], v2 = xr[tid + 512];
    float mu = blocksum256(v0 + v1 + v2, red) * (1.f / Cn);
    float d0 = v0 - mu, d1 = v1 - mu, d2 = v2 - mu;
    float var = blocksum256(d0 * d0 + d1 * d1 + d2 * d2, red) * (1.f / Cn);
    float rs = rsqrtf(var + LN_EPS);
    float* orow = out + (size_t)blockIdx.x * Cn;
    orow[tid]       = d0 * rs * w[tid]       + b[tid];
    orow[tid + 256] = d1 * rs * w[tid + 256] + b[tid + 256];
    orow[tid + 512] = d2 * rs * w[tid + 512] + b[tid + 512];
}

// ---------------- token-shift mixes -> packed bf16 A matrices ----------------
// Mq [BT][3072]: sec0=xr, sec1=xk, sec2=xv, sec3=xg
__global__ __launch_bounds__(256) void k_mix4(const float* __restrict__ xn,
        const float* __restrict__ mk, const float* __restrict__ mv,
        const float* __restrict__ mr, const float* __restrict__ mg,
        bf16* __restrict__ Mq) {
    int i = blockIdx.x * 256 + threadIdx.x;          // < BT*C
    int c = i % Cn;
    int row = i / Cn;
    int t = row & (Tn - 1);
    float cur = xn[i];
    float prev = (t == 0) ? 0.f : xn[i - Cn];
    float xx = prev - cur;
    size_t o = (size_t)row * RS + c;
    Mq[o]          = __float2bfloat16(cur + xx * mr[c]);
    Mq[o + 768]    = __float2bfloat16(cur + xx * mk[c]);
    Mq[o + 1536]   = __float2bfloat16(cur + xx * mv[c]);
    Mq[o + 2304]   = __float2bfloat16(cur + xx * mg[c]);
}
// Mc [BT][1536]: sec0=xk, sec1=xr
__global__ __launch_bounds__(256) void k_mix2(const float* __restrict__ xn,
        const float* __restrict__ mk, const float* __restrict__ mr,
        bf16* __restrict__ Mc) {
    int i = blockIdx.x * 256 + threadIdx.x;
    int c = i % Cn;
    int row = i / Cn;
    int t = row & (Tn - 1);
    float cur = xn[i];
    float prev = (t == 0) ? 0.f : xn[i - Cn];
    float xx = prev - cur;
    size_t o = (size_t)row * 1536 + c;
    Mc[o]       = __float2bfloat16(cur + xx * mk[c]);
    Mc[o + 768] = __float2bfloat16(cur + xx * mr[c]);
}

// ---------------- MFMA GEMM (m97 structure) ----------------
// C[4096, N] = act(A_bf16[4096, lda] @ WT_bf16[N, K]^T + bias[N])
// modes: 0=RKVG (out fp32 Rq, silu on col>=2304, A section by n0/768)
//        1=OUT  (out fp32 X +=, N=768)
//        2=CKR  (col<2304: relu^2 -> bf16 H3; else sigmoid -> fp32 Rr)
//        3=CV   (out fp32 Hv, N=768)
#define M_RKVG 0
#define M_OUT  1
#define M_CKR  2
#define M_CV   3
template<int MODE>
__global__ __launch_bounds__(256) void k_mfma(
        const bf16* __restrict__ A, int lda,
        const bf16* __restrict__ WT, int K,
        const float* __restrict__ bias,
        float* __restrict__ o1, bf16* __restrict__ o2) {
    __shared__ bf16 As[128 * 32];
    __shared__ bf16 Bs[128 * 32];
    const int tid = threadIdx.x;
    const int wave = tid >> 6, lane = tid & 63;
    const int m0 = blockIdx.y * 128, n0 = blockIdx.x * 128;
    int aoff = 0;
    if (MODE == M_RKVG) aoff = (n0 / 768) * 768;
    if (MODE == M_CKR)  aoff = (n0 >= 2304) ? 768 : 0;

    const int r_a = lane >> 2;          // row within 16-row staging group
    const int c_a = (lane & 3) * 8;     // bf16 col (16B granules)
    const int wm = (wave >> 1) * 64, wn = (wave & 1) * 64;
    const int fm = lane & 15, fk = (lane >> 4) * 8;

    f32x4 acc[4][4] = {};

    for (int kb = 0; kb < K; kb += 32) {
#pragma unroll
        for (int q = 0; q < 2; ++q) {
            int g = wave * 2 + q;
            int row = g * 16 + r_a;
            const bf16* gpa = A + (size_t)(m0 + row) * lda + aoff + kb + c_a;
            __builtin_amdgcn_global_load_lds(
                (const __attribute__((address_space(1))) void*)gpa,
                (__attribute__((address_space(3))) void*)(As + g * 512), 16, 0, 0);
            const bf16* gpb = WT + (size_t)(n0 + row) * K + kb + c_a;
            __builtin_amdgcn_global_load_lds(
                (const __attribute__((address_space(1))) void*)gpb,
                (__attribute__((address_space(3))) void*)(Bs + g * 512), 16, 0, 0);
        }
        __syncthreads();
        bf16x8 af[4], bfr[4];
#pragma unroll
        for (int i = 0; i < 4; ++i)
            af[i] = *(const bf16x8*)(As + (wm + i * 16 + fm) * 32 + fk);
#pragma unroll
        for (int j = 0; j < 4; ++j)
            bfr[j] = *(const bf16x8*)(Bs + (wn + j * 16 + fm) * 32 + fk);
#pragma unroll
        for (int i = 0; i < 4; ++i)
#pragma unroll
            for (int j = 0; j < 4; ++j)
                acc[i][j] = __builtin_amdgcn_mfma_f32_16x16x32_bf16(
                    af[i], bfr[j], acc[i][j], 0, 0, 0);
        __syncthreads();
    }

    const int er = lane >> 4;   // row quad
    const int ec = lane & 15;   // col
#pragma unroll
    for (int j = 0; j < 4; ++j) {
        int colg = n0 + wn + j * 16 + ec;
        float bv = bias[colg];
#pragma unroll
        for (int i = 0; i < 4; ++i) {
#pragma unroll
            for (int r = 0; r < 4; ++r) {
                int rowg = m0 + wm + i * 16 + er * 4 + r;
                float v = acc[i][j][r] + bv;
                if (MODE == M_RKVG) {
                    if (colg >= 2304) v = v / (1.f + __expf(-v));
                    o1[(size_t)rowg * RS + colg] = v;
                } else if (MODE == M_OUT) {
                    size_t o = (size_t)rowg * Cn + colg;
                    o1[o] += v;
                } else if (MODE == M_CKR) {
                    if (n0 < 2304) {
                        float rl = fmaxf(v, 0.f);
                        o2[(size_t)rowg * C3n + colg] = __float2bfloat16(rl * rl);
                    } else {
                        v = 1.f / (1.f + __expf(-v));
                        o1[(size_t)rowg * Cn + colg - 2304] = v;
                    }
                } else {
                    o1[(size_t)rowg * Cn + colg] = v;
                }
            }
        }
    }
}

// ---------------- attention: per-chunk state contribution ----------------
// kbuf/vbuf point into Rq (stride RS). A_c[m,n] = sum_j k[j][m]*w^(Q-1-j)*v[j][n]
__global__ __launch_bounds__(256) void k_chunkA(const float* __restrict__ kbuf,
        const float* __restrict__ vbuf, const float* __restrict__ td,
        float* __restrict__ Abuf) {
    int c = blockIdx.x & 3;
    int bh = blockIdx.x >> 2;
    int h = bh % Hn, b = bh / Hn;
    float lw = -__expf(td[h]);
    __shared__ float kd[8][64], vl[8][64];
    int tn = threadIdx.x & 63;
    int tm0 = (threadIdx.x >> 6) * 16;
    float acc[16] = {};
    const size_t base = ((size_t)(b * Tn + c * Qn)) * RS + h * Nn;
    int jr = threadIdx.x >> 6;
    for (int j0 = 0; j0 < Qn; j0 += 8) {
#pragma unroll
        for (int rr = 0; rr < 2; ++rr) {
            int jj = jr + rr * 4;
            int j = j0 + jj;
            float dec = __expf(lw * (float)(Qn - 1 - j));
            kd[jj][tn] = kbuf[base + (size_t)j * RS + tn] * dec;
            vl[jj][tn] = vbuf[base + (size_t)j * RS + tn];
        }
        __syncthreads();
#pragma unroll
        for (int j = 0; j < 8; ++j) {
            float vv = vl[j][tn];
#pragma unroll
            for (int m = 0; m < 16; ++m)
                acc[m] = fmaf(kd[j][tm0 + m], vv, acc[m]);
        }
        __syncthreads();
    }
    size_t ao = ((size_t)blockIdx.x * Nn + tm0) * Nn + tn;
#pragma unroll
    for (int m = 0; m < 16; ++m) Abuf[ao + (size_t)m * Nn] = acc[m];
}

// ---------------- attention: prefix over chunks ----------------
__global__ __launch_bounds__(256) void k_prefix(const float* __restrict__ Abuf,
        const float* __restrict__ td, float* __restrict__ Sbuf) {
    int h = blockIdx.x % Hn;
    float lw = -__expf(td[h]);
    float ws = __expf(lw * (float)Qn);
    size_t base = (size_t)blockIdx.x * NCn * Nn * Nn;
    for (int e = threadIdx.x; e < Nn * Nn; e += 256) {
        float s = 0.f;
#pragma unroll
        for (int c = 0; c < NCn; ++c) {
            Sbuf[base + (size_t)c * Nn * Nn + e] = s;
            s = ws * s + Abuf[base + (size_t)c * Nn * Nn + e];
        }
    }
}

// ---------------- attention: y for a 64-row block of a chunk ----------------
// r/k/v read from Rq (stride RS); y written to Yb (stride Cn)
__global__ __launch_bounds__(256) void k_attny(const float* __restrict__ rbuf,
        const float* __restrict__ kbuf, const float* __restrict__ vbuf,
        const float* __restrict__ Sbuf, const float* __restrict__ td,
        const float* __restrict__ tf, float* __restrict__ ybuf) {
    int x = blockIdx.x;
    int ib = x & 3; x >>= 2;
    int c = x & 3;
    int bh = x >> 2;
    int h = bh % Hn, b = bh / Hn;
    float lw = -__expf(td[h]);
    float u = tf[h];
    __shared__ float rl[64][65];
    __shared__ float tl[64][65];
    __shared__ float att[64][257];
    const int i0 = ib * 64;
    const size_t rowbase = ((size_t)(b * Tn + c * Qn)) * RS + h * Nn;
    const int tn = threadIdx.x & 63;
    const int tg = threadIdx.x >> 6;
    const int ii0 = (threadIdx.x >> 4) * 4;
    const int cc0 = (threadIdx.x & 15) * 4;

#pragma unroll
    for (int rr = 0; rr < 16; ++rr) {
        int i = tg * 16 + rr;
        rl[i][tn] = rbuf[rowbase + (size_t)(i0 + i) * RS + tn];
    }
    __syncthreads();

    for (int jt = 0; jt <= ib; ++jt) {
#pragma unroll
        for (int rr = 0; rr < 16; ++rr) {
            int j = tg * 16 + rr;
            tl[j][tn] = kbuf[rowbase + (size_t)(jt * 64 + j) * RS + tn];
        }
        __syncthreads();
        float a4[4][4] = {};
#pragma unroll 4
        for (int m = 0; m < 64; ++m) {
            float rv[4], kv[4];
#pragma unroll
            for (int q = 0; q < 4; ++q) { rv[q] = rl[ii0 + q][m]; kv[q] = tl[cc0 + q][m]; }
#pragma unroll
            for (int aa = 0; aa < 4; ++aa)
#pragma unroll
                for (int bb = 0; bb < 4; ++bb)
                    a4[aa][bb] = fmaf(rv[aa], kv[bb], a4[aa][bb]);
        }
#pragma unroll
        for (int aa = 0; aa < 4; ++aa)
#pragma unroll
            for (int bb = 0; bb < 4; ++bb) {
                int i = i0 + ii0 + aa;
                int j = jt * 64 + cc0 + bb;
                int d = i - j;
                float f = (d > 0) ? __expf(lw * (float)(d - 1)) : ((d == 0) ? u : 0.f);
                att[ii0 + aa][j] = a4[aa][bb] * f;
            }
        __syncthreads();
    }

    {
        size_t sbase = ((size_t)bh * NCn + c) * (Nn * Nn);
#pragma unroll
        for (int rr = 0; rr < 16; ++rr) {
            int m = tg * 16 + rr;
            tl[m][tn] = Sbuf[sbase + (size_t)m * Nn + tn];
        }
        __syncthreads();
    }
    float yacc[4][4] = {};
#pragma unroll 4
    for (int m = 0; m < 64; ++m) {
        float rv[4], sv[4];
#pragma unroll
        for (int q = 0; q < 4; ++q) { rv[q] = rl[ii0 + q][m]; sv[q] = tl[m][cc0 + q]; }
#pragma unroll
        for (int aa = 0; aa < 4; ++aa)
#pragma unroll
            for (int bb = 0; bb < 4; ++bb)
                yacc[aa][bb] = fmaf(rv[aa], sv[bb], yacc[aa][bb]);
    }
#pragma unroll
    for (int aa = 0; aa < 4; ++aa) {
        float f = __expf(lw * (float)(i0 + ii0 + aa));
#pragma unroll
        for (int bb = 0; bb < 4; ++bb) yacc[aa][bb] *= f;
    }
    __syncthreads();

    for (int jt = 0; jt <= ib; ++jt) {
#pragma unroll
        for (int rr = 0; rr < 16; ++rr) {
            int j = tg * 16 + rr;
            tl[j][tn] = vbuf[rowbase + (size_t)(jt * 64 + j) * RS + tn];
        }
        __syncthreads();
#pragma unroll 4
        for (int j = 0; j < 64; ++j) {
            float av[4], vv[4];
#pragma unroll
            for (int q = 0; q < 4; ++q) { av[q] = att[ii0 + q][jt * 64 + j]; vv[q] = tl[j][cc0 + q]; }
#pragma unroll
            for (int aa = 0; aa < 4; ++aa)
#pragma unroll
                for (int bb = 0; bb < 4; ++bb)
                    yacc[aa][bb] = fmaf(av[aa], vv[bb], yacc[aa][bb]);
        }
        __syncthreads();
    }

    size_t ybase = ((size_t)(b * Tn + c * Qn)) * Cn + h * Nn;
#pragma unroll
    for (int aa = 0; aa < 4; ++aa)
#pragma unroll
        for (int bb = 0; bb < 4; ++bb)
            ybuf[ybase + (size_t)(i0 + ii0 + aa) * Cn + cc0 + bb] = yacc[aa][bb];
}

// ---------------- groupnorm + gate -> bf16 ----------------
// y fp32 [BT][768]; g = Rq+2304 (stride RS, silu already applied); out bf16 [BT][768]
__global__ __launch_bounds__(768) void k_gngate(const float* __restrict__ y,
        const float* __restrict__ g, const float* __restrict__ gw,
        const float* __restrict__ gb, bf16* __restrict__ out) {
    int t = blockIdx.x;
    int h = threadIdx.x >> 6, n = threadIdx.x & 63;
    size_t o = (size_t)t * Cn + h * 64 + n;
    float v = y[o];
    float s = v;
#pragma unroll
    for (int q = 32; q > 0; q >>= 1) s += __shfl_xor(s, q, 64);
    float mu = s * (1.f / 64.f);
    float d = v - mu;
    float qq = d * d;
#pragma unroll
    for (int q = 32; q > 0; q >>= 1) qq += __shfl_xor(qq, q, 64);
    float var = qq * (1.f / 64.f);
    float outv = d * rsqrtf(var + GN_EPS) * gw[h * 64 + n] + gb[h * 64 + n];
    out[o] = __float2bfloat16(outv * g[(size_t)t * RS + h * 64 + n]);
}

// ---------------- cmix combine: x += sig * hv ----------------
__global__ __launch_bounds__(256) void k_combine(float* __restrict__ x,
        const float* __restrict__ sg, const float* __restrict__ hv) {
    int i = blockIdx.x * 256 + threadIdx.x;
    x[i] = fmaf(sg[i], hv[i], x[i]);
}

// ---------------- head ----------------
__global__ __launch_bounds__(256) void k_head(const float* __restrict__ xf,
        const float* __restrict__ wte, float* __restrict__ out) {
    __shared__ float red[4][4];
    int v = blockIdx.x;
    int tid = threadIdx.x;
    const float* wr = wte + (size_t)v * Cn;
    float a0 = 0, a1 = 0, a2 = 0, a3 = 0;
    for (int c = tid; c < Cn; c += 256) {
        float wv = wr[c];
        a0 = fmaf(wv, xf[c], a0);
        a1 = fmaf(wv, xf[Cn + c], a1);
        a2 = fmaf(wv, xf[2 * Cn + c], a2);
        a3 = fmaf(wv, xf[3 * Cn + c], a3);
    }
#pragma unroll
    for (int o = 32; o > 0; o >>= 1) {
        a0 += __shfl_down(a0, o, 64); a1 += __shfl_down(a1, o, 64);
        a2 += __shfl_down(a2, o, 64); a3 += __shfl_down(a3, o, 64);
    }
    if ((tid & 63) == 0) {
        int w8 = tid >> 6;
        red[w8][0] = a0; red[w8][1] = a1; red[w8][2] = a2; red[w8][3] = a3;
    }
    __syncthreads();
    if (tid < 4)
        out[(size_t)tid * Vn + v] = red[0][tid] + red[1][tid] + red[2][tid] + red[3][tid];
}

// ---------------- launch ----------------
extern "C" void kernel_launch(void* const* d_in, const int* in_sizes, int n_in,
                              void* d_out, int out_size, void* d_ws, size_t ws_size,
                              hipStream_t stream) {
    const int*   idx    = (const int*)  d_in[0];
    const float* wte    = (const float*)d_in[1];
    const float* wpe    = (const float*)d_in[2];
    const float* ln1_w  = (const float*)d_in[3];
    const float* ln1_b  = (const float*)d_in[4];
    const float* ln2_w  = (const float*)d_in[5];
    const float* ln2_b  = (const float*)d_in[6];
    const float* maa_tk = (const float*)d_in[7];
    const float* maa_tv = (const float*)d_in[8];
    const float* maa_tr = (const float*)d_in[9];
    const float* maa_tg = (const float*)d_in[10];
    const float* tdecay = (const float*)d_in[11];
    const float* tfaaaa = (const float*)d_in[12];
    const float* Wr     = (const float*)d_in[13];
    const float* br     = (const float*)d_in[14];
    const float* Wk     = (const float*)d_in[15];
    const float* bk     = (const float*)d_in[16];
    const float* Wv     = (const float*)d_in[17];
    const float* bv     = (const float*)d_in[18];
    const float* Wg     = (const float*)d_in[19];
    const float* bg     = (const float*)d_in[20];
    const float* Wo     = (const float*)d_in[21];
    const float* bo     = (const float*)d_in[22];
    const float* gn_w   = (const float*)d_in[23];
    const float* gn_b   = (const float*)d_in[24];
    const float* cmaa_k = (const float*)d_in[25];
    const float* cmaa_r = (const float*)d_in[26];
    const float* Wck    = (const float*)d_in[27];
    const float* bck    = (const float*)d_in[28];
    const float* Wcv    = (const float*)d_in[29];
    const float* bcv    = (const float*)d_in[30];
    const float* Wcr    = (const float*)d_in[31];
    const float* bcr    = (const float*)d_in[32];
    const float* lnf_w  = (const float*)d_in[33];
    const float* lnf_b  = (const float*)d_in[34];
    float* out = (float*)d_out;

    char* wsb = (char*)d_ws;
    size_t off = 0;
    auto alloc = [&](size_t bytes) {
        void* p = wsb + off;
        off += (bytes + 255) & ~(size_t)255;
        return p;
    };
    const size_t SQ = (size_t)Cn * Cn;              // 589824
    bf16* WqT   = (bf16*)alloc((size_t)Ln * RS * Cn * 2);       // [L][3072][768]
    bf16* WoT   = (bf16*)alloc((size_t)Ln * SQ * 2);            // [L][768][768]
    bf16* WckrT = (bf16*)alloc((size_t)Ln * RS * Cn * 2);       // [L][3072][768]
    bf16* WcvT  = (bf16*)alloc((size_t)Ln * Cn * C3n * 2);      // [L][768][2304]
    float* bq   = (float*)alloc((size_t)Ln * RS * 4);
    float* bckr = (float*)alloc((size_t)Ln * RS * 4);
    float* X    = (float*)alloc((size_t)BTn * Cn * 4);
    float* XN   = (float*)alloc((size_t)BTn * Cn * 4);
    bf16* Mq    = (bf16*)alloc((size_t)BTn * RS * 2);           // alias: Yb
    bf16* Mc    = (bf16*)alloc((size_t)BTn * 1536 * 2);         // alias: Ybf
    float* Rq   = (float*)alloc((size_t)BTn * RS * 4);          // alias: Rr, Hv
    bf16* H3    = (bf16*)alloc((size_t)BTn * C3n * 2);
    float* Ab   = (float*)alloc((size_t)Bn * Hn * NCn * Nn * Nn * 4);
    float* Sb   = (float*)alloc((size_t)Bn * Hn * NCn * Nn * Nn * 4);
    float* XF   = (float*)alloc((size_t)Bn * Cn * 4);
    if (off > ws_size) return;  // workspace too small — will fail loudly

    float* Yb  = (float*)Mq;                 // 12.6 MB <= 25.2 MB
    bf16*  Ybf = (bf16*)Mc;                  // 6.3 MB <= 12.6 MB
    float* Rr  = Rq;                         // cmix-phase reuse of Rq
    float* Hv  = Rq + (size_t)BTn * Cn;

    const int EW = (BTn * Cn) / 256;
    dim3 gT12(12, 12, Ln), gT36(36, 12, Ln), gTcv(12, 36, Ln);
    dim3 gQ(24, 32);    // N=3072 MFMA grids
    dim3 gS(6, 32);     // N=768 MFMA grids

    // ---- per-launch weight repack (harness re-poisons ws every call) ----
    k_wt<<<gT12, 256, 0, stream>>>(Wr, WqT,                Cn, Cn, SQ, (size_t)RS * Cn);
    k_wt<<<gT12, 256, 0, stream>>>(Wk, WqT + SQ,           Cn, Cn, SQ, (size_t)RS * Cn);
    k_wt<<<gT12, 256, 0, stream>>>(Wv, WqT + 2 * SQ,       Cn, Cn, SQ, (size_t)RS * Cn);
    k_wt<<<gT12, 256, 0, stream>>>(Wg, WqT + 3 * SQ,       Cn, Cn, SQ, (size_t)RS * Cn);
    k_wt<<<gT12, 256, 0, stream>>>(Wo, WoT,                Cn, Cn, SQ, SQ);
    k_wt<<<gT36, 256, 0, stream>>>(Wck, WckrT,             C3n, Cn, (size_t)Cn * C3n, (size_t)RS * Cn);
    k_wt<<<gT12, 256, 0, stream>>>(Wcr, WckrT + (size_t)C3n * Cn, Cn, Cn, SQ, (size_t)RS * Cn);
    k_wt<<<gTcv, 256, 0, stream>>>(Wcv, WcvT,              Cn, C3n, (size_t)Cn * C3n, (size_t)Cn * C3n);
    k_packb4<<<(Ln * RS) / 256, 256, 0, stream>>>(br, bk, bv, bg, bq);
    k_packb2<<<(Ln * RS) / 256, 256, 0, stream>>>(bck, bcr, bckr);

    k_embed<<<BTn, 256, 0, stream>>>(idx, wte, wpe, X);

    for (int l = 0; l < Ln; ++l) {
        const float* td = tdecay + l * Hn;
        const float* tf = tfaaaa + l * Hn;
        const bf16* WqTl   = WqT + (size_t)l * RS * Cn;
        const bf16* WoTl   = WoT + (size_t)l * SQ;
        const bf16* WckrTl = WckrT + (size_t)l * RS * Cn;
        const bf16* WcvTl  = WcvT + (size_t)l * Cn * C3n;

        // ---- tmix ----
        k_ln<<<BTn, 256, 0, stream>>>(X, ln1_w + l * Cn, ln1_b + l * Cn, XN, 1, 0);
        k_mix4<<<EW, 256, 0, stream>>>(XN, maa_tk + l * Cn, maa_tv + l * Cn,
                                       maa_tr + l * Cn, maa_tg + l * Cn, Mq);
        k_mfma<M_RKVG><<<gQ, 256, 0, stream>>>(Mq, RS, WqTl, Cn, bq + l * RS, Rq, nullptr);
        k_chunkA<<<Bn * Hn * NCn, 256, 0, stream>>>(Rq + 768, Rq + 1536, td, Ab);
        k_prefix<<<Bn * Hn, 256, 0, stream>>>(Ab, td, Sb);
        k_attny<<<Bn * Hn * NCn * 4, 256, 0, stream>>>(Rq, Rq + 768, Rq + 1536,
                                                       Sb, td, tf, Yb);
        k_gngate<<<BTn, 768, 0, stream>>>(Yb, Rq + 2304, gn_w + l * Cn, gn_b + l * Cn, Ybf);
        k_mfma<M_OUT><<<gS, 256, 0, stream>>>(Ybf, Cn, WoTl, Cn, bo + l * Cn, X, nullptr);

        // ---- cmix ----
        k_ln<<<BTn, 256, 0, stream>>>(X, ln2_w + l * Cn, ln2_b + l * Cn, XN, 1, 0);
        k_mix2<<<EW, 256, 0, stream>>>(XN, cmaa_k + l * Cn, cmaa_r + l * Cn, Mc);
        k_mfma<M_CKR><<<gQ, 256, 0, stream>>>(Mc, 1536, WckrTl, Cn, bckr + l * RS, Rr, H3);
        k_mfma<M_CV><<<gS, 256, 0, stream>>>(H3, C3n, WcvTl, C3n, bcv + l * Cn, Hv, nullptr);
        k_combine<<<EW, 256, 0, stream>>>(X, Rr, Hv);
    }

    k_ln<<<Bn, 256, 0, stream>>>(X, lnf_w, lnf_b, XF, Tn, Tn - 1);
    k_head<<<Vn, 256, 0, stream>>>(XF, wte, out);
}